// Round 5
// baseline (755.934 us; speedup 1.0000x reference)
//
#include <hip/hip_runtime.h>
#include <hip/hip_fp16.h>

namespace {
constexpr int Bn = 64;
constexpr int Tn = 1024;
constexpr int Kn = 256;

typedef _Float16 half8 __attribute__((ext_vector_type(8)));
typedef float f32x4 __attribute__((ext_vector_type(4)));

// ---- DPP wave-64 reductions ----
template <int C>
__device__ __forceinline__ float dppmax1(float x) {
    int o = __builtin_bit_cast(int, x);
    int y = __builtin_amdgcn_update_dpp(o, o, C, 0xF, 0xF, false);
    return fmaxf(x, __builtin_bit_cast(float, y));
}
template <int C>
__device__ __forceinline__ float dppadd1(float x) {
    int y = __builtin_amdgcn_update_dpp(0, __builtin_bit_cast(int, x), C, 0xF, 0xF, true);
    return x + __builtin_bit_cast(float, y);
}
__device__ __forceinline__ float wave_max64(float x) {
    x = dppmax1<0x111>(x);
    x = dppmax1<0x112>(x);
    x = dppmax1<0x114>(x);
    x = dppmax1<0x118>(x);
    x = dppmax1<0x142>(x);  // row_bcast:15
    x = dppmax1<0x143>(x);  // row_bcast:31
    return __builtin_bit_cast(float,
        __builtin_amdgcn_readlane(__builtin_bit_cast(int, x), 63));
}
__device__ __forceinline__ float wave_sum64(float x) {
    x = dppadd1<0x111>(x);
    x = dppadd1<0x112>(x);
    x = dppadd1<0x114>(x);
    x = dppadd1<0x118>(x);
    x = dppadd1<0x142>(x);
    x = dppadd1<0x143>(x);
    return __builtin_bit_cast(float,
        __builtin_amdgcn_readlane(__builtin_bit_cast(int, x), 63));
}

__global__ __launch_bounds__(256, 1) void crf_kernel(
    const float* __restrict__ inputs,     // (B,T,K)
    const long long* __restrict__ tags,   // (B,T)
    const int* __restrict__ mask,         // (B,T)
    const float* __restrict__ trans,      // (K,K)
    const float* __restrict__ start_t,    // (K,)
    const float* __restrict__ end_t,      // (K,)
    float* __restrict__ out)              // scalar
{
    const int b   = blockIdx.x;
    const int tid = threadIdx.x;
    const int w   = tid >> 6;       // wave 0..3, owns j in [64w, 64w+64)
    const int l   = tid & 63;
    const int La  = l >> 4;         // 0..3
    const int lc  = l & 15;

    // unique tag per lane: lane's own N-tile is c = La
    const int j_own = 64 * w + 16 * La + lc;

    __shared__ __align__(16) _Float16 p_sh[2][Kn];  // double-buffered p row (f16)
    __shared__ __align__(16) float Mvf[2][4];       // per-wave alpha max (float4 read)
    __shared__ float red[4][2];
    __shared__ float sh_np;
    __shared__ int   sh_len;

    // ---- E as MFMA B-fragments:
    // Bfrag[c][kt] holds B[k = 32kt + 8La + i][n = 64w + 16c + lc] = exp(trans[k][n])
    half8 Bfrag[4][8];
#pragma unroll
    for (int c = 0; c < 4; ++c) {
        const int n = 64 * w + 16 * c + lc;
#pragma unroll
        for (int kt = 0; kt < 8; ++kt) {
            half8 hb;
#pragma unroll
            for (int i = 0; i < 8; ++i) {
                const int k = 32 * kt + 8 * La + i;
                hb[i] = (_Float16)__expf(trans[k * Kn + n]);
            }
            Bfrag[c][kt] = hb;
        }
    }

    if (tid == 0) { sh_len = 0; sh_np = 0.f; }
    __syncthreads();

    // ---- sequence length
    {
        int c = 0;
        for (int t = tid; t < Tn; t += 256) c += (mask[b * Tn + t] > 0) ? 1 : 0;
        float cf = wave_sum64((float)c);
        if (l == 0) atomicAdd(&sh_len, (int)(cf + 0.5f));
    }
    __syncthreads();
    const int end_idx = sh_len - 1;

    const float endj = end_t[j_own];
    const size_t bTK = (size_t)b * Tn * Kn;

    // ---- alpha init (t = 0), one j per lane
    float alpha = inputs[bTK + j_own] + start_t[j_own] +
                  (end_idx == 0 ? endj : 0.f);

    // ---- 3-deep prefetch of emissions + mask
    float lg1 = inputs[bTK + 1 * (size_t)Kn + j_own];
    int   mk1 = mask[b * Tn + 1];
    float lg2 = inputs[bTK + 2 * (size_t)Kn + j_own];
    int   mk2 = mask[b * Tn + 2];
    float lg3 = inputs[bTK + 3 * (size_t)Kn + j_own];
    int   mk3 = mask[b * Tn + 3];

    // ---- pre-loop: block max of alpha(0) -> scale for p(0)
    {
        const float wmx = wave_max64(alpha);
        if (l == 0) Mvf[0][w] = wmx;
    }
    __syncthreads();
    float R_prev;
    {
        const float4 mv = *(const float4*)(&Mvf[0][0]);
        R_prev = fmaxf(fmaxf(mv.x, mv.y), fmaxf(mv.z, mv.w));
        const float pv = __expf(fminf(alpha - R_prev, 11.0f));
        p_sh[0][j_own] = (_Float16)pv;
    }

    // ---- forward recursion, one barrier per step
    for (int t = 1; t < Tn; ++t) {
        __syncthreads();

        const int pb = (t - 1) & 1;   // buffer holding p(t-1), Mv(t-1)
        const int nb = t & 1;

        const float lgC = lg1;
        const int   mkC = mk1;
        lg1 = lg2; mk1 = mk2;
        lg2 = lg3; mk2 = mk3;
        const int tp = (t + 3 < Tn) ? (t + 3) : (Tn - 1);
        lg3 = inputs[bTK + (size_t)tp * Kn + j_own];
        mk3 = mask[b * Tn + tp];

        // R_next = max_j alpha(t-1): scale for this step's publish (ONE b128 read)
        const float4 mv = *(const float4*)(&Mvf[pb][0]);
        const float R_next = fmaxf(fmaxf(mv.x, mv.y), fmaxf(mv.z, mv.w));

        // A-fragments of replicated p: 8 broadcast b128 reads
        const half8* prow = (const half8*)(&p_sh[pb][0]);
        half8 af[8];
#pragma unroll
        for (int kt = 0; kt < 8; ++kt) af[kt] = prow[kt * 4 + La];

        // 4 N-tiles, chained over full K=256
        f32x4 acc0 = {0.f, 0.f, 0.f, 0.f};
        f32x4 acc1 = {0.f, 0.f, 0.f, 0.f};
        f32x4 acc2 = {0.f, 0.f, 0.f, 0.f};
        f32x4 acc3 = {0.f, 0.f, 0.f, 0.f};
#pragma unroll
        for (int kt = 0; kt < 8; ++kt) {
            acc0 = __builtin_amdgcn_mfma_f32_16x16x32_f16(af[kt], Bfrag[0][kt], acc0, 0, 0, 0);
            acc1 = __builtin_amdgcn_mfma_f32_16x16x32_f16(af[kt], Bfrag[1][kt], acc1, 0, 0, 0);
            acc2 = __builtin_amdgcn_mfma_f32_16x16x32_f16(af[kt], Bfrag[2][kt], acc2, 0, 0, 0);
            acc3 = __builtin_amdgcn_mfma_f32_16x16x32_f16(af[kt], Bfrag[3][kt], acc3, 0, 0, 0);
        }
        // D rows are replicated; lane's own tile is c = La, value for col lc at acc[0]
        const float s = (La == 0) ? acc0[0]
                      : (La == 1) ? acc1[0]
                      : (La == 2) ? acc2[0]
                                  : acc3[0];

        const float na = R_prev + __logf(s) + lgC + (t == end_idx ? endj : 0.f);
        if (mkC > 0) alpha = na;

        // publish p(t) with delayed scale; record wave max for next step
        const float pv = __expf(fminf(alpha - R_next, 11.0f));
        p_sh[nb][j_own] = (_Float16)pv;
        const float wmx = wave_max64(alpha);
        if (l == 0) Mvf[nb][w] = wmx;

        R_prev = R_next;
    }

    // ---- denominator = logsumexp over all 256 alphas (one per lane)
    {
        const float wm = wave_max64(alpha);
        const float ex = __expf(alpha - wm);
        const float sw = wave_sum64(ex);
        if (l == 0) { red[w][0] = wm; red[w][1] = sw; }
    }

    // ---- numerator (gather path score)
    float np = 0.f;
    for (int t = tid; t < Tn; t += 256) {
        const int   tg = (int)tags[b * Tn + t];
        const float e  = inputs[bTK + (size_t)t * Kn + tg];
        if (t == 0) {
            np += e + start_t[tg];
        } else {
            const float mf = (float)mask[b * Tn + t];
            const int   tq = (int)tags[b * Tn + t - 1];
            np += mf * (e + trans[tq * Kn + tg]);
        }
    }
    np = wave_sum64(np);
    if (l == 0) atomicAdd(&sh_np, np);
    __syncthreads();

    if (tid == 0) {
        float Rf = red[0][0];
#pragma unroll
        for (int q = 1; q < 4; ++q) Rf = fmaxf(Rf, red[q][0]);
        float S = 0.f;
#pragma unroll
        for (int q = 0; q < 4; ++q) S += red[q][1] * __expf(red[q][0] - Rf);
        const float denom = Rf + __logf(S);
        const float numer = sh_np + end_t[(int)tags[b * Tn + end_idx]];
        atomicAdd(out, numer - denom);
    }
}

}  // namespace

extern "C" void kernel_launch(void* const* d_in, const int* in_sizes, int n_in,
                              void* d_out, int out_size, void* d_ws, size_t ws_size,
                              hipStream_t stream) {
    const float*     inputs  = (const float*)d_in[0];
    const long long* tags    = (const long long*)d_in[1];
    const int*       mask    = (const int*)d_in[2];
    const float*     trans   = (const float*)d_in[3];
    const float*     start_t = (const float*)d_in[4];
    const float*     end_t   = (const float*)d_in[5];
    float* out = (float*)d_out;

    hipMemsetAsync(out, 0, sizeof(float), stream);
    crf_kernel<<<dim3(Bn), dim3(256), 0, stream>>>(inputs, tags, mask, trans,
                                                   start_t, end_t, out);
}